// Round 6
// baseline (2834.274 us; speedup 1.0000x reference)
//
#include <hip/hip_runtime.h>
#include <math.h>

#define HID 128
#define NRAYS 4096

__device__ __forceinline__ float sp_f(float x){        // jax.nn.softplus, stable
  return fmaxf(x, 0.0f) + log1pf(expf(-fabsf(x)));
}
__device__ __forceinline__ float sg_f(float x){        // sigmoid
  return 1.0f / (1.0f + expf(-x));
}

// ---------------------------------------------------------------- transpose W2
__global__ void k_transpose(const float* __restrict__ W2, float* __restrict__ W2T){
  int idx = blockIdx.x*256 + threadIdx.x;
  if (idx < HID*HID){
    int k = idx >> 7, n = idx & 127;
    W2T[n*HID + k] = W2[k*HID + n];
  }
}

// ---------------------------------------------------------------- initial z + pts
__global__ void k_init(const float* __restrict__ rays_o, const float* __restrict__ rays_d,
                       const float* __restrict__ nearv, const float* __restrict__ farv,
                       float* __restrict__ z_buf, float* __restrict__ pts){
  int idx = blockIdx.x*256 + threadIdx.x;
  if (idx >= NRAYS*64) return;
  int ray = idx >> 6, j = idx & 63;
  float nr = nearv[ray];
  float z = nr + (farv[ray] - nr) * ((float)j / 63.0f);
  z_buf[ray*128 + j] = z;
  pts[idx*3+0] = rays_o[ray*3+0] + rays_d[ray*3+0]*z;
  pts[idx*3+1] = rays_o[ray*3+1] + rays_d[ray*3+1]*z;
  pts[idx*3+2] = rays_o[ray*3+2] + rays_d[ray*3+2]*z;
}

// ---------------------------------------------------------------- fp32 MLP (fwd / fwd+grad)
// 128 points/block, 256 threads; lane pair (2j,2j+1) shares point j: each lane
// owns k-half [64*half, 64*half+64). h[64] and dh[64] in registers. W2T rows
// ([n][k], pre-transposed) staged once in LDS; per-n reads are same-address
// b128 broadcasts (conflict-free), serving fwd dot AND bwd axpy.
template<int GRAD>
__global__ __launch_bounds__(256, 2) void k_mlp2(
    const float* __restrict__ pts,
    const float* __restrict__ W1, const float* __restrict__ b1,
    const float* __restrict__ W2T, const float* __restrict__ b2,
    const float* __restrict__ W3, const float* __restrict__ b3,
    float* __restrict__ sdf_out, float* __restrict__ grad_out)
{
  __shared__ float sW[HID*HID];     // W2T [n][k]  (64 KB)
  __shared__ float sW1[3*HID];
  __shared__ float sB1[HID], sB2[HID], sW3[HID];
  const int tid  = threadIdx.x;
  const int half = tid & 1;
  const int p    = blockIdx.x*128 + (tid >> 1);
  const int kb   = half << 6;       // this lane's k-base

  {
    const float4* src = (const float4*)W2T;
    float4* dst = (float4*)sW;
    for (int i = tid; i < HID*HID/4; i += 256) dst[i] = src[i];
  }
  if (tid < HID){
    sB1[tid] = b1[tid]; sB2[tid] = b2[tid]; sW3[tid] = W3[tid];
    sW1[tid] = W1[tid]; sW1[HID+tid] = W1[HID+tid]; sW1[2*HID+tid] = W1[2*HID+tid];
  }
  const float x0 = pts[p*3+0];
  const float x1 = pts[p*3+1];
  const float x2 = pts[p*3+2];
  __syncthreads();

  // layer 1: lane's 64 k-rows (same fmaf order as R2: b1, +x0, +x1, +x2)
  float h[64];
  #pragma unroll
  for (int i = 0; i < 64; i++){
    int k = kb + i;
    float pre = fmaf(x2, sW1[2*HID+k], fmaf(x1, sW1[HID+k], fmaf(x0, sW1[k], sB1[k])));
    h[i] = sp_f(pre);
  }

  float dh[64];
  if (GRAD){
    #pragma unroll
    for (int i = 0; i < 64; i++) dh[i] = 0.0f;
  }
  float sdfacc = 0.0f;

  #pragma unroll 2
  for (int n = 0; n < HID; n++){
    const float4* wr = (const float4*)&sW[(n << 7) + kb];
    float a0 = 0.f, a1 = 0.f, a2 = 0.f, a3 = 0.f;
    #pragma unroll
    for (int c = 0; c < 16; c++){
      float4 wv = wr[c];
      a0 = fmaf(h[4*c+0], wv.x, a0);
      a1 = fmaf(h[4*c+1], wv.y, a1);
      a2 = fmaf(h[4*c+2], wv.z, a2);
      a3 = fmaf(h[4*c+3], wv.w, a3);
    }
    float pre2 = (a0 + a1) + (a2 + a3);
    pre2 += __shfl_xor(pre2, 1, 64);      // merge halves -> both lanes hold full dot
    pre2 += sB2[n];
    const float w3 = sW3[n];
    sdfacc += sp_f(pre2) * w3;
    if (GRAD){
      const float g2 = sg_f(pre2) * w3;
      #pragma unroll
      for (int c = 0; c < 16; c++){
        float4 wv = wr[c];                // broadcast re-read (cheap, conflict-free)
        dh[4*c+0] = fmaf(g2, wv.x, dh[4*c+0]);
        dh[4*c+1] = fmaf(g2, wv.y, dh[4*c+1]);
        dh[4*c+2] = fmaf(g2, wv.z, dh[4*c+2]);
        dh[4*c+3] = fmaf(g2, wv.w, dh[4*c+3]);
      }
    }
  }

  if (half == 0) sdf_out[p] = sdfacc + b3[0];

  if (GRAD){
    float gx = 0.f, gy = 0.f, gz = 0.f;
    #pragma unroll
    for (int i = 0; i < 64; i++){
      int k = kb + i;
      float w1x = sW1[k], w1y = sW1[HID+k], w1z = sW1[2*HID+k];
      float pre1 = fmaf(x2, w1z, fmaf(x1, w1y, fmaf(x0, w1x, sB1[k])));
      float d = dh[i] * sg_f(pre1);
      gx = fmaf(w1x, d, gx);
      gy = fmaf(w1y, d, gy);
      gz = fmaf(w1z, d, gz);
    }
    gx += __shfl_xor(gx, 1, 64);
    gy += __shfl_xor(gy, 1, 64);
    gz += __shfl_xor(gz, 1, 64);
    if (half == 0){
      grad_out[p*3+0] = gx;
      grad_out[p*3+1] = gy;
      grad_out[p*3+2] = gz;
    }
  }
}

// ---------------------------------------------------------------- scatters
__global__ void k_scatter_init(const float* __restrict__ sdf_tmp, float* __restrict__ sdf_buf){
  int idx = blockIdx.x*256 + threadIdx.x;
  if (idx >= NRAYS*64) return;
  sdf_buf[(idx >> 6)*128 + (idx & 63)] = sdf_tmp[idx];
}
__global__ void k_scatter_new(const float* __restrict__ sdf_tmp, const int* __restrict__ slots,
                              float* __restrict__ sdf_buf){
  int idx = blockIdx.x*256 + threadIdx.x;
  if (idx >= NRAYS*16) return;
  sdf_buf[(idx >> 4)*128 + slots[idx]] = sdf_tmp[idx];
}

// ---------------------------------------------------------------- upsample (one wave per ray)
__global__ __launch_bounds__(64) void k_upsample(
      const float* __restrict__ rays_o, const float* __restrict__ rays_d,
      float* __restrict__ z_buf, float* __restrict__ sdf_buf,
      float* __restrict__ pts_new, int* __restrict__ slots,
      int S, float inv_s, int last){
  __shared__ float z[128], sd[128], rad[128], cosv[128], alf[128], wv[128], cdf[129], nz[16];
  __shared__ int slt[16];
  const int ray = blockIdx.x;
  const int l   = threadIdx.x;
  const float ox = rays_o[ray*3], oy = rays_o[ray*3+1], oz = rays_o[ray*3+2];
  const float dx = rays_d[ray*3], dy = rays_d[ray*3+1], dz = rays_d[ray*3+2];
  for (int j = l; j < S; j += 64){
    float zz = z_buf[ray*128+j];
    z[j]  = zz;
    sd[j] = sdf_buf[ray*128+j];
    float px = ox+dx*zz, py = oy+dy*zz, pz = oz+dz*zz;
    rad[j] = sqrtf(px*px + py*py + pz*pz);
  }
  __syncthreads();
  for (int j = l; j < S-1; j += 64)
    cosv[j] = (sd[j+1]-sd[j]) / (z[j+1]-z[j] + 1e-5f);
  __syncthreads();
  for (int j = l; j < S-1; j += 64){
    float cv = fminf((j > 0) ? cosv[j-1] : 0.0f, cosv[j]);
    cv = fminf(fmaxf(cv, -1000.0f), 0.0f);
    float inside = (rad[j] < 1.0f || rad[j+1] < 1.0f) ? 1.0f : 0.0f;
    cv *= inside;
    float mid  = 0.5f*(sd[j]+sd[j+1]);
    float dist = z[j+1]-z[j];
    float e = sg_f((mid - cv*dist*0.5f)*inv_s);
    float f = sg_f((mid + cv*dist*0.5f)*inv_s);
    alf[j] = (e - f + 1e-5f) / (e + 1e-5f);
  }
  __syncthreads();
  if (l == 0){
    float T = 1.0f, wsum = 0.0f;
    for (int j = 0; j < S-1; j++){
      float w = alf[j]*T + 1e-5f;
      wv[j] = w; wsum += w;
      T *= (1.0f - alf[j] + 1e-7f);
    }
    cdf[0] = 0.0f;
    float c = 0.0f;
    for (int j = 0; j < S-1; j++){ c += wv[j]/wsum; cdf[j+1] = c; }
  }
  __syncthreads();
  if (l < 16){
    float u = 0.03125f + 0.0625f*(float)l;
    int idx = 0;
    while (idx < S && cdf[idx] <= u) idx++;
    int below = idx - 1; if (below < 0) below = 0;
    int above = (idx < S-1) ? idx : (S-1);
    float cb = cdf[below], ca = cdf[above];
    float den = ca - cb; if (den < 1e-5f) den = 1.0f;
    float t = (u - cb) / den;
    nz[l] = z[below] + t*(z[above] - z[below]);
  }
  __syncthreads();
  if (l == 0){
    int i = S-1, j = 15;
    for (int dst = S+15; dst >= 0; --dst){
      bool takeOld = (j < 0) || (i >= 0 && z[i] > nz[j]);
      if (takeOld){ z[dst] = z[i]; sd[dst] = sd[i]; i--; }
      else        { z[dst] = nz[j]; slt[j] = dst; j--; }
    }
  }
  __syncthreads();
  for (int j = l; j < S+16; j += 64){
    z_buf[ray*128+j]  = z[j];
    sdf_buf[ray*128+j] = sd[j];
  }
  if (!last && l < 16){
    slots[ray*16+l] = slt[l];
    float zz = nz[l];
    pts_new[(ray*16+l)*3+0] = ox + dx*zz;
    pts_new[(ray*16+l)*3+1] = oy + dy*zz;
    pts_new[(ray*16+l)*3+2] = oz + dz*zz;
  }
}

// ---------------------------------------------------------------- final mid-point pts
__global__ void k_prep(const float* __restrict__ rays_o, const float* __restrict__ rays_d,
                       const float* __restrict__ z_buf, float* __restrict__ pts){
  int idx = blockIdx.x*256 + threadIdx.x;
  if (idx >= NRAYS*128) return;
  int ray = idx >> 7, s = idx & 127;
  float z = z_buf[idx];
  float d = (s < 127) ? (z_buf[idx+1] - z) : 0.03125f;
  float mid = z + 0.5f*d;
  pts[idx*3+0] = rays_o[ray*3+0] + rays_d[ray*3+0]*mid;
  pts[idx*3+1] = rays_o[ray*3+1] + rays_d[ray*3+1]*mid;
  pts[idx*3+2] = rays_o[ray*3+2] + rays_d[ray*3+2]*mid;
}

// ---------------------------------------------------------------- render (one thread per ray)
__global__ void k_render(const float* __restrict__ z_buf, const float* __restrict__ sdf_mid,
                         const float* __restrict__ rays_d, const float* __restrict__ grad,
                         const float* __restrict__ variance, float* __restrict__ depth_out){
  int ray = blockIdx.x*64 + threadIdx.x;
  if (ray >= NRAYS) return;
  float inv_s = expf(10.0f * variance[0]);
  inv_s = fminf(fmaxf(inv_s, 1e-6f), 1e6f);
  const float dx = rays_d[ray*3], dy = rays_d[ray*3+1], dz = rays_d[ray*3+2];
  float T = 1.0f, depth = 0.0f;
  float zc = z_buf[ray*128];
  for (int s = 0; s < 128; s++){
    int idx = ray*128 + s;
    float zn = (s < 127) ? z_buf[idx+1] : zc;
    float d  = (s < 127) ? (zn - zc) : 0.03125f;
    float sdf = sdf_mid[idx];
    float gx = grad[idx*3], gy = grad[idx*3+1], gz = grad[idx*3+2];
    float tc = dx*gx + dy*gy + dz*gz;
    float ic = -fmaxf(0.5f - 0.5f*tc, 0.0f);
    float e = sg_f((sdf - ic*d*0.5f)*inv_s);
    float f = sg_f((sdf + ic*d*0.5f)*inv_s);
    float a = (e - f + 1e-5f) / (e + 1e-5f);
    a = fminf(fmaxf(a, 0.0f), 1.0f);
    depth += a*T*zc;
    T *= (1.0f - a + 1e-7f);
    zc = zn;
  }
  depth_out[ray] = depth;
}

// ---------------------------------------------------------------- launcher
extern "C" void kernel_launch(void* const* d_in, const int* in_sizes, int n_in,
                              void* d_out, int out_size, void* d_ws, size_t ws_size,
                              hipStream_t stream){
  (void)in_sizes; (void)n_in; (void)out_size; (void)ws_size;
  const float* rays_o = (const float*)d_in[0];
  const float* rays_d = (const float*)d_in[1];
  const float* nearv  = (const float*)d_in[2];
  const float* farv   = (const float*)d_in[3];
  const float* W1 = (const float*)d_in[4];
  const float* b1 = (const float*)d_in[5];
  const float* W2 = (const float*)d_in[6];
  const float* b2 = (const float*)d_in[7];
  const float* W3 = (const float*)d_in[8];
  const float* b3 = (const float*)d_in[9];
  const float* variance = (const float*)d_in[10];

  float* ws      = (float*)d_ws;
  float* z_buf   = ws;                    // 4096*128
  float* sdf_buf = ws + 524288;           // 4096*128
  float* sdf_tmp = ws + 1048576;          // up to 524288
  float* W2T     = ws + 1572864;          // 16384
  int*   slots   = (int*)(ws + 1589248);  // 4096*16 ints

  float* out       = (float*)d_out;
  float* depth_out = out;
  float* grad_out  = out + NRAYS;         // 524288*3 floats
  float* pts       = grad_out;            // pts staging aliases grad region

  k_transpose<<<dim3(64), dim3(256), 0, stream>>>(W2, W2T);
  k_init<<<dim3(1024), dim3(256), 0, stream>>>(rays_o, rays_d, nearv, farv, z_buf, pts);
  k_mlp2<0><<<dim3(2048), dim3(256), 0, stream>>>(pts, W1,b1, W2T, b2, W3,b3,
                                                  sdf_tmp, (float*)nullptr);
  k_scatter_init<<<dim3(1024), dim3(256), 0, stream>>>(sdf_tmp, sdf_buf);

  for (int i = 0; i < 4; i++){
    int S = 64 + 16*i;
    float inv_s = (float)(64 << i);
    int last = (i == 3) ? 1 : 0;
    k_upsample<<<dim3(4096), dim3(64), 0, stream>>>(rays_o, rays_d, z_buf, sdf_buf,
                                                    pts, slots, S, inv_s, last);
    if (!last){
      k_mlp2<0><<<dim3(512), dim3(256), 0, stream>>>(pts, W1,b1, W2T, b2, W3,b3,
                                                     sdf_tmp, (float*)nullptr);
      k_scatter_new<<<dim3(256), dim3(256), 0, stream>>>(sdf_tmp, slots, sdf_buf);
    }
  }

  k_prep<<<dim3(2048), dim3(256), 0, stream>>>(rays_o, rays_d, z_buf, pts);
  k_mlp2<1><<<dim3(4096), dim3(256), 0, stream>>>(pts, W1,b1, W2T, b2, W3,b3,
                                                  sdf_tmp, grad_out);
  k_render<<<dim3(64), dim3(64), 0, stream>>>(z_buf, sdf_tmp, rays_d, grad_out,
                                              variance, depth_out);
}

// Round 7
// 2314.501 us; speedup vs baseline: 1.2246x; 1.2246x over previous
//
#include <hip/hip_runtime.h>
#include <math.h>

#define HID 128
#define NRAYS 4096

__device__ __forceinline__ float sp_f(float x){        // jax.nn.softplus, stable
  return fmaxf(x, 0.0f) + log1pf(expf(-fabsf(x)));
}
__device__ __forceinline__ float sg_f(float x){        // sigmoid
  return 1.0f / (1.0f + expf(-x));
}
__device__ __forceinline__ unsigned short f2bf(float x){   // fp32 -> bf16 (RNE)
  unsigned u = __float_as_uint(x);
  unsigned r = u + 0x7FFFu + ((u >> 16) & 1u);
  return (unsigned short)(r >> 16);
}
__device__ __forceinline__ float bf2f(unsigned h){
  return __uint_as_float(h << 16);
}
// force a pointer to be wave-uniform -> scalar (s_load) path for weight rows
__device__ __forceinline__ const float* uni(const float* p){
  unsigned long long v = (unsigned long long)p;
  unsigned lo = __builtin_amdgcn_readfirstlane((unsigned)v);
  unsigned hi = __builtin_amdgcn_readfirstlane((unsigned)(v >> 32));
  return (const float*)(((unsigned long long)hi << 32) | lo);
}

// ---------------------------------------------------------------- transpose W2
__global__ void k_transpose(const float* __restrict__ W2, float* __restrict__ W2T){
  int idx = blockIdx.x*256 + threadIdx.x;
  if (idx < HID*HID){
    int k = idx >> 7, n = idx & 127;
    W2T[n*HID + k] = W2[k*HID + n];
  }
}

// ---------------------------------------------------------------- initial z + pts
__global__ void k_init(const float* __restrict__ rays_o, const float* __restrict__ rays_d,
                       const float* __restrict__ nearv, const float* __restrict__ farv,
                       float* __restrict__ z_buf, float* __restrict__ pts){
  int idx = blockIdx.x*256 + threadIdx.x;
  if (idx >= NRAYS*64) return;
  int ray = idx >> 6, j = idx & 63;
  float nr = nearv[ray];
  float z = nr + (farv[ray] - nr) * ((float)j / 63.0f);
  z_buf[ray*128 + j] = z;
  pts[idx*3+0] = rays_o[ray*3+0] + rays_d[ray*3+0]*z;
  pts[idx*3+1] = rays_o[ray*3+1] + rays_d[ray*3+1]*z;
  pts[idx*3+2] = rays_o[ray*3+2] + rays_d[ray*3+2]*z;
}

// ---------------------------------------------------------------- fp32 MLP (fwd / fwd+grad)
// 128 threads/block, one point per lane. h[128] (and dh[128] in phase B) in
// registers; W2T rows are wave-uniform scalar loads (SGPR broadcast) -> pure
// v_fmac hot loop, no LDS/VMEM in the K-loop, weights amortized over 64
// points/wave. GRAD: g2 spilled to LDS as packed bf16x2 (own-row only), dh
// accumulated in a second pass over the same (L1-hot) weight rows.
template<int GRAD>
__global__ __launch_bounds__(128, 2) void k_mlp3(
    const float* __restrict__ pts,
    const float* __restrict__ W1g, const float* __restrict__ b1g,
    const float* __restrict__ W2Tg, const float* __restrict__ b2g,
    const float* __restrict__ W3g, const float* __restrict__ b3g,
    float* __restrict__ sdf_out, float* __restrict__ grad_out)
{
  extern __shared__ unsigned sG[];      // GRAD only: [128][68] packed bf16x2 g2
  const float* W1  = uni(W1g);
  const float* b1  = uni(b1g);
  const float* W2T = uni(W2Tg);
  const float* b2  = uni(b2g);
  const float* W3  = uni(W3g);
  const float* b3  = uni(b3g);
  const int tid = threadIdx.x;
  const int p   = blockIdx.x*128 + tid;
  const float x0 = pts[p*3+0];
  const float x1 = pts[p*3+1];
  const float x2 = pts[p*3+2];

  // layer 1: all 128 rows per lane, scalar weights
  float h[128];
  #pragma unroll
  for (int k = 0; k < 128; k++){
    float pre = fmaf(x2, W1[2*HID+k], fmaf(x1, W1[HID+k], fmaf(x0, W1[k], b1[k])));
    h[k] = sp_f(pre);
  }

  // phase A: pre2[n] = h . W2T[n][:]; sdf accumulation (+ g2 spill if GRAD)
  float sdfacc = 0.0f;
  float g2e = 0.0f;
  #pragma unroll 2
  for (int n = 0; n < 128; n++){
    const float4* wr = (const float4*)(W2T + (n << 7));
    float a0 = 0.f, a1 = 0.f, a2 = 0.f, a3 = 0.f;
    #pragma unroll
    for (int c = 0; c < 32; c++){
      float4 wv = wr[c];
      a0 = fmaf(h[4*c+0], wv.x, a0);
      a1 = fmaf(h[4*c+1], wv.y, a1);
      a2 = fmaf(h[4*c+2], wv.z, a2);
      a3 = fmaf(h[4*c+3], wv.w, a3);
    }
    float pre2 = ((a0 + a1) + (a2 + a3)) + b2[n];
    const float w3 = W3[n];
    sdfacc += sp_f(pre2) * w3;
    if (GRAD){
      float g2 = sg_f(pre2) * w3;
      if (n & 1) sG[tid*68 + (n >> 1)] = ((unsigned)f2bf(g2) << 16) | f2bf(g2e);
      else       g2e = g2;
    }
  }
  sdf_out[p] = sdfacc + b3[0];

  if (GRAD){
    __syncthreads();
    // phase B: dh[k] = sum_n g2[n] * W2T[n][k]
    float dh[128];
    #pragma unroll
    for (int i = 0; i < 128; i++) dh[i] = 0.0f;
    for (int n8 = 0; n8 < 16; n8++){
      uint4 gpk = *(const uint4*)&sG[tid*68 + 4*n8];
      unsigned gu[4] = {gpk.x, gpk.y, gpk.z, gpk.w};
      #pragma unroll 2
      for (int t = 0; t < 8; t++){
        int n = 8*n8 + t;
        float g2 = bf2f((t & 1) ? (gu[t>>1] >> 16) : (gu[t>>1] & 0xFFFFu));
        const float4* wr = (const float4*)(W2T + (n << 7));
        #pragma unroll
        for (int c = 0; c < 32; c++){
          float4 wv = wr[c];
          dh[4*c+0] = fmaf(g2, wv.x, dh[4*c+0]);
          dh[4*c+1] = fmaf(g2, wv.y, dh[4*c+1]);
          dh[4*c+2] = fmaf(g2, wv.z, dh[4*c+2]);
          dh[4*c+3] = fmaf(g2, wv.w, dh[4*c+3]);
        }
      }
    }
    // epilogue: dp1 = dh * sigmoid(pre1) (pre1 recomputed), grad = W1 @ dp1
    float gx = 0.f, gy = 0.f, gz = 0.f;
    #pragma unroll
    for (int k = 0; k < 128; k++){
      float w1x = W1[k], w1y = W1[HID+k], w1z = W1[2*HID+k];
      float pre1 = fmaf(x2, w1z, fmaf(x1, w1y, fmaf(x0, w1x, b1[k])));
      float d = dh[k] * sg_f(pre1);
      gx = fmaf(w1x, d, gx);
      gy = fmaf(w1y, d, gy);
      gz = fmaf(w1z, d, gz);
    }
    grad_out[p*3+0] = gx;
    grad_out[p*3+1] = gy;
    grad_out[p*3+2] = gz;
  }
}

// ---------------------------------------------------------------- scatters
__global__ void k_scatter_init(const float* __restrict__ sdf_tmp, float* __restrict__ sdf_buf){
  int idx = blockIdx.x*256 + threadIdx.x;
  if (idx >= NRAYS*64) return;
  sdf_buf[(idx >> 6)*128 + (idx & 63)] = sdf_tmp[idx];
}
__global__ void k_scatter_new(const float* __restrict__ sdf_tmp, const int* __restrict__ slots,
                              float* __restrict__ sdf_buf){
  int idx = blockIdx.x*256 + threadIdx.x;
  if (idx >= NRAYS*16) return;
  sdf_buf[(idx >> 4)*128 + slots[idx]] = sdf_tmp[idx];
}

// ---------------------------------------------------------------- upsample (one wave per ray)
__global__ __launch_bounds__(64) void k_upsample(
      const float* __restrict__ rays_o, const float* __restrict__ rays_d,
      float* __restrict__ z_buf, float* __restrict__ sdf_buf,
      float* __restrict__ pts_new, int* __restrict__ slots,
      int S, float inv_s, int last){
  __shared__ float z[128], sd[128], rad[128], cosv[128], alf[128], wv[128], cdf[129], nz[16];
  __shared__ int slt[16];
  const int ray = blockIdx.x;
  const int l   = threadIdx.x;
  const float ox = rays_o[ray*3], oy = rays_o[ray*3+1], oz = rays_o[ray*3+2];
  const float dx = rays_d[ray*3], dy = rays_d[ray*3+1], dz = rays_d[ray*3+2];
  for (int j = l; j < S; j += 64){
    float zz = z_buf[ray*128+j];
    z[j]  = zz;
    sd[j] = sdf_buf[ray*128+j];
    float px = ox+dx*zz, py = oy+dy*zz, pz = oz+dz*zz;
    rad[j] = sqrtf(px*px + py*py + pz*pz);
  }
  __syncthreads();
  for (int j = l; j < S-1; j += 64)
    cosv[j] = (sd[j+1]-sd[j]) / (z[j+1]-z[j] + 1e-5f);
  __syncthreads();
  for (int j = l; j < S-1; j += 64){
    float cv = fminf((j > 0) ? cosv[j-1] : 0.0f, cosv[j]);
    cv = fminf(fmaxf(cv, -1000.0f), 0.0f);
    float inside = (rad[j] < 1.0f || rad[j+1] < 1.0f) ? 1.0f : 0.0f;
    cv *= inside;
    float mid  = 0.5f*(sd[j]+sd[j+1]);
    float dist = z[j+1]-z[j];
    float e = sg_f((mid - cv*dist*0.5f)*inv_s);
    float f = sg_f((mid + cv*dist*0.5f)*inv_s);
    alf[j] = (e - f + 1e-5f) / (e + 1e-5f);
  }
  __syncthreads();
  if (l == 0){
    float T = 1.0f, wsum = 0.0f;
    for (int j = 0; j < S-1; j++){
      float w = alf[j]*T + 1e-5f;
      wv[j] = w; wsum += w;
      T *= (1.0f - alf[j] + 1e-7f);
    }
    cdf[0] = 0.0f;
    float c = 0.0f;
    for (int j = 0; j < S-1; j++){ c += wv[j]/wsum; cdf[j+1] = c; }
  }
  __syncthreads();
  if (l < 16){
    float u = 0.03125f + 0.0625f*(float)l;
    int idx = 0;
    while (idx < S && cdf[idx] <= u) idx++;
    int below = idx - 1; if (below < 0) below = 0;
    int above = (idx < S-1) ? idx : (S-1);
    float cb = cdf[below], ca = cdf[above];
    float den = ca - cb; if (den < 1e-5f) den = 1.0f;
    float t = (u - cb) / den;
    nz[l] = z[below] + t*(z[above] - z[below]);
  }
  __syncthreads();
  if (l == 0){
    int i = S-1, j = 15;
    for (int dst = S+15; dst >= 0; --dst){
      bool takeOld = (j < 0) || (i >= 0 && z[i] > nz[j]);
      if (takeOld){ z[dst] = z[i]; sd[dst] = sd[i]; i--; }
      else        { z[dst] = nz[j]; slt[j] = dst; j--; }
    }
  }
  __syncthreads();
  for (int j = l; j < S+16; j += 64){
    z_buf[ray*128+j]  = z[j];
    sdf_buf[ray*128+j] = sd[j];
  }
  if (!last && l < 16){
    slots[ray*16+l] = slt[l];
    float zz = nz[l];
    pts_new[(ray*16+l)*3+0] = ox + dx*zz;
    pts_new[(ray*16+l)*3+1] = oy + dy*zz;
    pts_new[(ray*16+l)*3+2] = oz + dz*zz;
  }
}

// ---------------------------------------------------------------- final mid-point pts
__global__ void k_prep(const float* __restrict__ rays_o, const float* __restrict__ rays_d,
                       const float* __restrict__ z_buf, float* __restrict__ pts){
  int idx = blockIdx.x*256 + threadIdx.x;
  if (idx >= NRAYS*128) return;
  int ray = idx >> 7, s = idx & 127;
  float z = z_buf[idx];
  float d = (s < 127) ? (z_buf[idx+1] - z) : 0.03125f;
  float mid = z + 0.5f*d;
  pts[idx*3+0] = rays_o[ray*3+0] + rays_d[ray*3+0]*mid;
  pts[idx*3+1] = rays_o[ray*3+1] + rays_d[ray*3+1]*mid;
  pts[idx*3+2] = rays_o[ray*3+2] + rays_d[ray*3+2]*mid;
}

// ---------------------------------------------------------------- render (one thread per ray)
__global__ void k_render(const float* __restrict__ z_buf, const float* __restrict__ sdf_mid,
                         const float* __restrict__ rays_d, const float* __restrict__ grad,
                         const float* __restrict__ variance, float* __restrict__ depth_out){
  int ray = blockIdx.x*64 + threadIdx.x;
  if (ray >= NRAYS) return;
  float inv_s = expf(10.0f * variance[0]);
  inv_s = fminf(fmaxf(inv_s, 1e-6f), 1e6f);
  const float dx = rays_d[ray*3], dy = rays_d[ray*3+1], dz = rays_d[ray*3+2];
  float T = 1.0f, depth = 0.0f;
  float zc = z_buf[ray*128];
  for (int s = 0; s < 128; s++){
    int idx = ray*128 + s;
    float zn = (s < 127) ? z_buf[idx+1] : zc;
    float d  = (s < 127) ? (zn - zc) : 0.03125f;
    float sdf = sdf_mid[idx];
    float gx = grad[idx*3], gy = grad[idx*3+1], gz = grad[idx*3+2];
    float tc = dx*gx + dy*gy + dz*gz;
    float ic = -fmaxf(0.5f - 0.5f*tc, 0.0f);
    float e = sg_f((sdf - ic*d*0.5f)*inv_s);
    float f = sg_f((sdf + ic*d*0.5f)*inv_s);
    float a = (e - f + 1e-5f) / (e + 1e-5f);
    a = fminf(fmaxf(a, 0.0f), 1.0f);
    depth += a*T*zc;
    T *= (1.0f - a + 1e-7f);
    zc = zn;
  }
  depth_out[ray] = depth;
}

// ---------------------------------------------------------------- launcher
extern "C" void kernel_launch(void* const* d_in, const int* in_sizes, int n_in,
                              void* d_out, int out_size, void* d_ws, size_t ws_size,
                              hipStream_t stream){
  (void)in_sizes; (void)n_in; (void)out_size; (void)ws_size;
  const float* rays_o = (const float*)d_in[0];
  const float* rays_d = (const float*)d_in[1];
  const float* nearv  = (const float*)d_in[2];
  const float* farv   = (const float*)d_in[3];
  const float* W1 = (const float*)d_in[4];
  const float* b1 = (const float*)d_in[5];
  const float* W2 = (const float*)d_in[6];
  const float* b2 = (const float*)d_in[7];
  const float* W3 = (const float*)d_in[8];
  const float* b3 = (const float*)d_in[9];
  const float* variance = (const float*)d_in[10];

  float* ws      = (float*)d_ws;
  float* z_buf   = ws;                    // 4096*128
  float* sdf_buf = ws + 524288;           // 4096*128
  float* sdf_tmp = ws + 1048576;          // up to 524288
  float* W2T     = ws + 1572864;          // 16384
  int*   slots   = (int*)(ws + 1589248);  // 4096*16 ints

  float* out       = (float*)d_out;
  float* depth_out = out;
  float* grad_out  = out + NRAYS;         // 524288*3 floats
  float* pts       = grad_out;            // pts staging aliases grad region

  const size_t g2_lds = 128 * 68 * sizeof(unsigned);   // 34816 B

  k_transpose<<<dim3(64), dim3(256), 0, stream>>>(W2, W2T);
  k_init<<<dim3(1024), dim3(256), 0, stream>>>(rays_o, rays_d, nearv, farv, z_buf, pts);
  k_mlp3<0><<<dim3(2048), dim3(128), 0, stream>>>(pts, W1,b1, W2T, b2, W3,b3,
                                                  sdf_tmp, (float*)nullptr);
  k_scatter_init<<<dim3(1024), dim3(256), 0, stream>>>(sdf_tmp, sdf_buf);

  for (int i = 0; i < 4; i++){
    int S = 64 + 16*i;
    float inv_s = (float)(64 << i);
    int last = (i == 3) ? 1 : 0;
    k_upsample<<<dim3(4096), dim3(64), 0, stream>>>(rays_o, rays_d, z_buf, sdf_buf,
                                                    pts, slots, S, inv_s, last);
    if (!last){
      k_mlp3<0><<<dim3(512), dim3(128), 0, stream>>>(pts, W1,b1, W2T, b2, W3,b3,
                                                     sdf_tmp, (float*)nullptr);
      k_scatter_new<<<dim3(256), dim3(256), 0, stream>>>(sdf_tmp, slots, sdf_buf);
    }
  }

  k_prep<<<dim3(2048), dim3(256), 0, stream>>>(rays_o, rays_d, z_buf, pts);
  k_mlp3<1><<<dim3(4096), dim3(128), g2_lds, stream>>>(pts, W1,b1, W2T, b2, W3,b3,
                                                       sdf_tmp, grad_out);
  k_render<<<dim3(64), dim3(64), 0, stream>>>(z_buf, sdf_tmp, rays_d, grad_out,
                                              variance, depth_out);
}